// Round 3
// baseline (1437.599 us; speedup 1.0000x reference)
//
#include <hip/hip_runtime.h>
#include <math.h>

#define NLEV 16
#define TBL (1u << 19)
#define TMASK (TBL - 1u)

typedef float f32x4 __attribute__((ext_vector_type(4)));

struct ScaleArgs { float s[NLEV]; };

// Rotated level loop: OFF is the starting level for this XCD, so at any given
// moment all waves on one XCD hammer the same ~1 level's 4MB table -> it stays
// resident in that XCD's 4MB L2. Template keeps `l` compile-time so acc[]
// stays in registers (runtime-indexed arrays spill to scratch).
template<int OFF>
__device__ __forceinline__ void encode_all(float px, float py, float pz,
                                           const float* __restrict__ W,
                                           const ScaleArgs& sc,
                                           float* __restrict__ acc)
{
    #pragma unroll
    for (int i = 0; i < NLEV; ++i) {
        const int l = (i + OFF) & (NLEV - 1);
        float s = sc.s[l];
        float ux = px * s, uy = py * s, uz = pz * s;
        int ix = (int)ux, iy = (int)uy, iz = (int)uz;   // trunc == floor (x >= 0)
        float dx = ux - (float)ix;
        float dy = uy - (float)iy;
        float dz = uz - (float)iz;

        unsigned a0 = (unsigned)ix;
        unsigned a1 = (unsigned)iy * 2654435761u;
        unsigned a2 = (unsigned)iz * 805459861u;
        unsigned b0 = a0 + 1u;
        unsigned b1 = a1 + 2654435761u;
        unsigned b2 = a2 + 805459861u;

        const float* Wl = W + (size_t)l * TBL * 2u;
        float ax = 0.f, ay = 0.f;

        #pragma unroll
        for (int v = 0; v < 8; ++v) {
            unsigned h = ((v & 1) ? b0 : a0) ^ ((v & 2) ? b1 : a1) ^ ((v & 4) ? b2 : a2);
            h &= TMASK;
            float wx = (v & 1) ? dx : 1.f - dx;
            float wy = (v & 2) ? dy : 1.f - dy;
            float wz = (v & 4) ? dz : 1.f - dz;
            float w = (wx * wy) * wz;   // matches wts.prod left fold
            const float2 fv = *reinterpret_cast<const float2*>(Wl + (size_t)h * 2u);
            ax = fmaf(fv.x, w, ax);
            ay = fmaf(fv.y, w, ay);
        }
        acc[2 * l + 0] = ax;
        acc[2 * l + 1] = ay;
    }
}

__global__ __launch_bounds__(256)
void hashenc(const float* __restrict__ x, const float* __restrict__ W,
             float* __restrict__ out, ScaleArgs sc, int N)
{
    int n = blockIdx.x * blockDim.x + threadIdx.x;
    if (n >= N) return;

    // x is streamed exactly once -> nontemporal, don't pollute L2
    float px = __builtin_nontemporal_load(&x[(size_t)n * 3 + 0]);
    float py = __builtin_nontemporal_load(&x[(size_t)n * 3 + 1]);
    float pz = __builtin_nontemporal_load(&x[(size_t)n * 3 + 2]);

    float acc[2 * NLEV];

    // blockIdx.x % 8 ~ XCD id (round-robin dispatch heuristic). Wrong mapping
    // only costs speed, never correctness.
    switch (blockIdx.x & 7) {
        case 0: encode_all<0>(px, py, pz, W, sc, acc); break;
        case 1: encode_all<2>(px, py, pz, W, sc, acc); break;
        case 2: encode_all<4>(px, py, pz, W, sc, acc); break;
        case 3: encode_all<6>(px, py, pz, W, sc, acc); break;
        case 4: encode_all<8>(px, py, pz, W, sc, acc); break;
        case 5: encode_all<10>(px, py, pz, W, sc, acc); break;
        case 6: encode_all<12>(px, py, pz, W, sc, acc); break;
        case 7: encode_all<14>(px, py, pz, W, sc, acc); break;
    }

    // 128B contiguous row per thread; output never re-read -> nontemporal
    f32x4* o = reinterpret_cast<f32x4*>(out + (size_t)n * (2 * NLEV));
    #pragma unroll
    for (int j = 0; j < 8; ++j) {
        f32x4 v = { acc[4 * j + 0], acc[4 * j + 1],
                    acc[4 * j + 2], acc[4 * j + 3] };
        __builtin_nontemporal_store(v, &o[j]);
    }
}

extern "C" void kernel_launch(void* const* d_in, const int* in_sizes, int n_in,
                              void* d_out, int out_size, void* d_ws, size_t ws_size,
                              hipStream_t stream) {
    const float* x = (const float*)d_in[0];
    const float* W = (const float*)d_in[1];
    float* out = (float*)d_out;
    int N = in_sizes[0] / 3;

    // replicate numpy: b = exp((log(2048)-log(16))/16); scale_l = float32(16 * b**l)
    ScaleArgs sc;
    double b = exp((log(2048.0) - log(16.0)) / 16.0);
    for (int l = 0; l < NLEV; ++l) {
        double p;
        switch (l) {
            case 0: p = 1.0; break;
            case 1: p = b;   break;
            case 2: p = b * b; break;
            default: p = pow(b, (double)l); break;
        }
        sc.s[l] = (float)(16.0 * p);
    }

    int block = 256;
    int grid = (N + block - 1) / block;
    hipLaunchKernelGGL(hashenc, dim3(grid), dim3(block), 0, stream,
                       x, W, out, sc, N);
}

// Round 4
// 944.923 us; speedup vs baseline: 1.5214x; 1.5214x over previous
//
#include <hip/hip_runtime.h>
#include <math.h>

#define NLEV 16
#define TBLN (1u << 19)
#define TMASK (TBLN - 1u)
#define NPT 4   // points batched per thread in level kernels (gather MLP)

typedef float f32x2 __attribute__((ext_vector_type(2)));
typedef float f32x4 __attribute__((ext_vector_type(4)));

struct ScaleArgs { float s[NLEV]; };

// ---------------- level-major path ----------------
// One kernel per level: every wave device-wide gathers from the SAME 4MB
// table -> resident in each XCD's 4MB L2 (compulsory 32MB/level from L3).
// Results go to transposed scratch sc[n*2] (full-line NT stores).
__global__ __launch_bounds__(256)
void level_kernel(const float* __restrict__ x, const float* __restrict__ Wl,
                  float* __restrict__ sc, float scale, int N, int TOT)
{
    int t = blockIdx.x * blockDim.x + threadIdx.x;
    if (t >= TOT) return;

    int nn[NPT];
    float dx[NPT], dy[NPT], dz[NPT];
    unsigned a0[NPT], a1[NPT], a2[NPT];
    f32x2 fv[NPT][8];

    // phase 1: load x (NT: streamed, keep table lines in L2), compute bases
    #pragma unroll
    for (int i = 0; i < NPT; ++i) {
        int n = t + i * TOT;
        if (n > N - 1) n = N - 1;          // benign duplicate (same value written)
        nn[i] = n;
        float px = __builtin_nontemporal_load(&x[(size_t)n * 3 + 0]);
        float py = __builtin_nontemporal_load(&x[(size_t)n * 3 + 1]);
        float pz = __builtin_nontemporal_load(&x[(size_t)n * 3 + 2]);
        float ux = px * scale, uy = py * scale, uz = pz * scale;
        int ix = (int)ux, iy = (int)uy, iz = (int)uz;   // trunc == floor (x>=0)
        dx[i] = ux - (float)ix;
        dy[i] = uy - (float)iy;
        dz[i] = uz - (float)iz;
        a0[i] = (unsigned)ix;
        a1[i] = (unsigned)iy * 2654435761u;
        a2[i] = (unsigned)iz * 805459861u;
    }

    // phase 2: issue all 8*NPT independent gathers (regular loads -> cache in L2)
    #pragma unroll
    for (int i = 0; i < NPT; ++i) {
        unsigned b0 = a0[i] + 1u, b1 = a1[i] + 2654435761u, b2 = a2[i] + 805459861u;
        #pragma unroll
        for (int v = 0; v < 8; ++v) {
            unsigned h = ((v & 1) ? b0 : a0[i]) ^ ((v & 2) ? b1 : a1[i]) ^ ((v & 4) ? b2 : a2[i]);
            h &= TMASK;
            fv[i][v] = *reinterpret_cast<const f32x2*>(Wl + (size_t)h * 2u);
        }
    }

    // phase 3: trilinear reduce (same fold order as reference), NT full-line store
    #pragma unroll
    for (int i = 0; i < NPT; ++i) {
        float ax = 0.f, ay = 0.f;
        #pragma unroll
        for (int v = 0; v < 8; ++v) {
            float wx = (v & 1) ? dx[i] : 1.f - dx[i];
            float wy = (v & 2) ? dy[i] : 1.f - dy[i];
            float wz = (v & 4) ? dz[i] : 1.f - dz[i];
            float w = (wx * wy) * wz;
            ax = fmaf(fv[i][v].x, w, ax);
            ay = fmaf(fv[i][v].y, w, ay);
        }
        f32x2 r = { ax, ay };
        __builtin_nontemporal_store(r, reinterpret_cast<f32x2*>(sc + (size_t)nn[i] * 2u));
    }
}

// Gather the 16 levels' f32x2 back into 128B rows. Scratch reads are
// lane-contiguous (512B/wave); out stores regular so L2 merges lines.
__global__ __launch_bounds__(256)
void transpose_kernel(const float* __restrict__ sc, float* __restrict__ out, int N)
{
    int n = blockIdx.x * blockDim.x + threadIdx.x;
    if (n >= N) return;
    float r[2 * NLEV];
    #pragma unroll
    for (int l = 0; l < NLEV; ++l) {
        f32x2 v = __builtin_nontemporal_load(
            reinterpret_cast<const f32x2*>(sc + ((size_t)l * N + n) * 2u));
        r[2 * l + 0] = v.x;
        r[2 * l + 1] = v.y;
    }
    f32x4* o = reinterpret_cast<f32x4*>(out + (size_t)n * (2 * NLEV));
    #pragma unroll
    for (int j = 0; j < 8; ++j) {
        f32x4 v = { r[4 * j + 0], r[4 * j + 1], r[4 * j + 2], r[4 * j + 3] };
        o[j] = v;   // regular store: let L2 merge the 16B pieces into full lines
    }
}

// ---------------- fallback (round-1 kernel, known-good) ----------------
__global__ __launch_bounds__(256)
void hashenc_fallback(const float* __restrict__ x, const float* __restrict__ W,
                      float* __restrict__ out, ScaleArgs sc, int N)
{
    int n = blockIdx.x * blockDim.x + threadIdx.x;
    if (n >= N) return;
    float px = x[(size_t)n * 3 + 0];
    float py = x[(size_t)n * 3 + 1];
    float pz = x[(size_t)n * 3 + 2];
    float acc[2 * NLEV];
    #pragma unroll
    for (int l = 0; l < NLEV; ++l) {
        float s = sc.s[l];
        float ux = px * s, uy = py * s, uz = pz * s;
        int ix = (int)ux, iy = (int)uy, iz = (int)uz;
        float dx = ux - (float)ix, dy = uy - (float)iy, dz = uz - (float)iz;
        unsigned a0 = (unsigned)ix;
        unsigned a1 = (unsigned)iy * 2654435761u;
        unsigned a2 = (unsigned)iz * 805459861u;
        unsigned b0 = a0 + 1u, b1 = a1 + 2654435761u, b2 = a2 + 805459861u;
        const float* Wl = W + (size_t)l * TBLN * 2u;
        float ax = 0.f, ay = 0.f;
        #pragma unroll
        for (int v = 0; v < 8; ++v) {
            unsigned h = ((v & 1) ? b0 : a0) ^ ((v & 2) ? b1 : a1) ^ ((v & 4) ? b2 : a2);
            h &= TMASK;
            float wx = (v & 1) ? dx : 1.f - dx;
            float wy = (v & 2) ? dy : 1.f - dy;
            float wz = (v & 4) ? dz : 1.f - dz;
            float w = (wx * wy) * wz;
            const float2 fvv = *reinterpret_cast<const float2*>(Wl + (size_t)h * 2u);
            ax = fmaf(fvv.x, w, ax);
            ay = fmaf(fvv.y, w, ay);
        }
        acc[2 * l + 0] = ax;
        acc[2 * l + 1] = ay;
    }
    float4* o = reinterpret_cast<float4*>(out + (size_t)n * (2 * NLEV));
    #pragma unroll
    for (int j = 0; j < 8; ++j)
        o[j] = make_float4(acc[4 * j + 0], acc[4 * j + 1], acc[4 * j + 2], acc[4 * j + 3]);
}

extern "C" void kernel_launch(void* const* d_in, const int* in_sizes, int n_in,
                              void* d_out, int out_size, void* d_ws, size_t ws_size,
                              hipStream_t stream) {
    const float* x = (const float*)d_in[0];
    const float* W = (const float*)d_in[1];
    float* out = (float*)d_out;
    int N = in_sizes[0] / 3;

    // numpy-exact scales: b = exp((log(2048)-log(16))/16); s_l = float32(16*b**l)
    ScaleArgs sc;
    double b = exp((log(2048.0) - log(16.0)) / 16.0);
    for (int l = 0; l < NLEV; ++l) {
        double p;
        switch (l) {
            case 0: p = 1.0; break;
            case 1: p = b;   break;
            case 2: p = b * b; break;
            default: p = pow(b, (double)l); break;
        }
        sc.s[l] = (float)(16.0 * p);
    }

    size_t need = (size_t)NLEV * (size_t)N * 2u * sizeof(float);
    if (ws_size >= need) {
        float* scratch = (float*)d_ws;
        int TOT = (N + NPT - 1) / NPT;
        int gl = (TOT + 255) / 256;
        for (int l = 0; l < NLEV; ++l) {
            hipLaunchKernelGGL(level_kernel, dim3(gl), dim3(256), 0, stream,
                               x, W + (size_t)l * TBLN * 2u,
                               scratch + (size_t)l * (size_t)N * 2u,
                               sc.s[l], N, TOT);
        }
        int gt = (N + 255) / 256;
        hipLaunchKernelGGL(transpose_kernel, dim3(gt), dim3(256), 0, stream,
                           scratch, out, N);
    } else {
        int grid = (N + 255) / 256;
        hipLaunchKernelGGL(hashenc_fallback, dim3(grid), dim3(256), 0, stream,
                           x, W, out, sc, N);
    }
}

// Round 5
// 732.334 us; speedup vs baseline: 1.9630x; 1.2903x over previous
//
#include <hip/hip_runtime.h>
#include <hip/hip_fp16.h>
#include <math.h>

#define NLEV 16
#define TBLN (1u << 19)
#define TMASK (TBLN - 1u)
#define NPT 4   // points batched per thread in level kernels (gather MLP)
#define PR1 2654435761u
#define PR2 805459861u

typedef float f32x4 __attribute__((ext_vector_type(4)));
typedef unsigned int u32;
typedef unsigned int u32x2 __attribute__((ext_vector_type(2)));
typedef unsigned int u32x4 __attribute__((ext_vector_type(4)));

struct ScaleArgs { float s[NLEV]; };

static __device__ __forceinline__ u32 packf2(float a, float b) {
    __half2 h = __floats2half2_rn(a, b);          // low16 = a, high16 = b
    return __builtin_bit_cast(u32, h);
}
static __device__ __forceinline__ float2 unpack16(u32 u) {
    __half2 h = __builtin_bit_cast(__half2, u);
    return __half22float2(h);                      // .x = low half
}

// W (f32 [L][T][2]) -> packed fp16 pairs [L][T] (one u32 per table entry)
__global__ __launch_bounds__(256)
void convert_w(const float* __restrict__ W, u32* __restrict__ Wh, int np4)
{
    int i = blockIdx.x * blockDim.x + threadIdx.x;
    if (i >= np4) return;
    const f32x4* src = reinterpret_cast<const f32x4*>(W) + (size_t)i * 2;
    f32x4 A = __builtin_nontemporal_load(src);
    f32x4 B = __builtin_nontemporal_load(src + 1);
    u32x4 o = { packf2(A.x, A.y), packf2(A.z, A.w),
                packf2(B.x, B.y), packf2(B.z, B.w) };
    __builtin_nontemporal_store(o, reinterpret_cast<u32x4*>(Wh) + i);
}

// One kernel per level: all waves device-wide hammer the same 2MB fp16 table
// -> L2-resident per XCD. Even-ix trick: x-dim prime is 1, so corners
// (ix, y, z) and (ix+1, y, z) hash to h and h^1 when ix is even -> both live
// in one aligned 8B chunk -> single u32x2 load for the pair (4 loads instead
// of 8 for half the points).
__global__ __launch_bounds__(256)
void level_kernel(const float* __restrict__ x, const u32* __restrict__ Wl,
                  u32* __restrict__ sc, float scale, int N, int TOT)
{
    int t = blockIdx.x * blockDim.x + threadIdx.x;
    if (t >= TOT) return;

    int nn[NPT];
    float dx[NPT], dy[NPT], dz[NPT];
    u32 a0[NPT], a1[NPT], a2[NPT];
    u32 fv[NPT][8];

    // phase 1: x loads (NT: streamed once per kernel, don't evict table)
    #pragma unroll
    for (int i = 0; i < NPT; ++i) {
        int n = t + i * TOT;
        if (n > N - 1) n = N - 1;          // duplicate write of same value: benign
        nn[i] = n;
        float px = __builtin_nontemporal_load(&x[(size_t)n * 3 + 0]);
        float py = __builtin_nontemporal_load(&x[(size_t)n * 3 + 1]);
        float pz = __builtin_nontemporal_load(&x[(size_t)n * 3 + 2]);
        float ux = px * scale, uy = py * scale, uz = pz * scale;
        int ix = (int)ux, iy = (int)uy, iz = (int)uz;   // trunc == floor (x>=0)
        dx[i] = ux - (float)ix;
        dy[i] = uy - (float)iy;
        dz[i] = uz - (float)iz;
        a0[i] = (unsigned)ix;
        a1[i] = (unsigned)iy * PR1;
        a2[i] = (unsigned)iz * PR2;
    }

    // phase 2: gathers (regular loads -> cached in L2)
    #pragma unroll
    for (int i = 0; i < NPT; ++i) {
        u32 b0 = a0[i] + 1u, b1 = a1[i] + PR1, b2 = a2[i] + PR2;
        // pair j covers corners v=2j (x=ix) and v=2j+1 (x=ix+1)
        u32 E[4] = { a1[i] ^ a2[i], b1 ^ a2[i], a1[i] ^ b2, b1 ^ b2 };
        if ((a0[i] & 1u) == 0u) {
            #pragma unroll
            for (int j = 0; j < 4; ++j) {
                u32 hl = (E[j] ^ a0[i]) & TMASK;       // h_hi = hl ^ 1
                u32x2 p = *reinterpret_cast<const u32x2*>(Wl + (hl & ~1u));
                u32 lo = (hl & 1u) ? p.y : p.x;
                u32 hi = (hl & 1u) ? p.x : p.y;
                fv[i][2 * j + 0] = lo;
                fv[i][2 * j + 1] = hi;
            }
        } else {
            #pragma unroll
            for (int j = 0; j < 4; ++j) {
                u32 hl = (E[j] ^ a0[i]) & TMASK;
                u32 hh = (E[j] ^ b0) & TMASK;
                fv[i][2 * j + 0] = Wl[hl];
                fv[i][2 * j + 1] = Wl[hh];
            }
        }
    }

    // phase 3: trilinear reduce, same fold order as reference; fp16 pack,
    // NT store (contiguous 4B/lane = full lines per wave)
    #pragma unroll
    for (int i = 0; i < NPT; ++i) {
        float ax = 0.f, ay = 0.f;
        #pragma unroll
        for (int v = 0; v < 8; ++v) {
            float wx = (v & 1) ? dx[i] : 1.f - dx[i];
            float wy = (v & 2) ? dy[i] : 1.f - dy[i];
            float wz = (v & 4) ? dz[i] : 1.f - dz[i];
            float w = (wx * wy) * wz;
            float2 f = unpack16(fv[i][v]);
            ax = fmaf(f.x, w, ax);
            ay = fmaf(f.y, w, ay);
        }
        __builtin_nontemporal_store(packf2(ax, ay), sc + nn[i]);
    }
}

// Assemble 128B output rows from fp16 scratch [l][n] -> out [n][32] f32.
__global__ __launch_bounds__(256)
void transpose_kernel(const u32* __restrict__ sc, float* __restrict__ out, int N)
{
    int n = blockIdx.x * blockDim.x + threadIdx.x;
    if (n >= N) return;
    float r[2 * NLEV];
    #pragma unroll
    for (int l = 0; l < NLEV; ++l) {
        u32 u = __builtin_nontemporal_load(sc + (size_t)l * N + n);
        float2 f = unpack16(u);
        r[2 * l + 0] = f.x;
        r[2 * l + 1] = f.y;
    }
    f32x4* o = reinterpret_cast<f32x4*>(out + (size_t)n * (2 * NLEV));
    #pragma unroll
    for (int j = 0; j < 8; ++j) {
        f32x4 v = { r[4 * j + 0], r[4 * j + 1], r[4 * j + 2], r[4 * j + 3] };
        o[j] = v;   // regular store: L2 merges 16B pieces into full lines
    }
}

// ---------------- fallback (round-1 kernel, known-good, f32 exact) ----------
__global__ __launch_bounds__(256)
void hashenc_fallback(const float* __restrict__ x, const float* __restrict__ W,
                      float* __restrict__ out, ScaleArgs sc, int N)
{
    int n = blockIdx.x * blockDim.x + threadIdx.x;
    if (n >= N) return;
    float px = x[(size_t)n * 3 + 0];
    float py = x[(size_t)n * 3 + 1];
    float pz = x[(size_t)n * 3 + 2];
    float acc[2 * NLEV];
    #pragma unroll
    for (int l = 0; l < NLEV; ++l) {
        float s = sc.s[l];
        float ux = px * s, uy = py * s, uz = pz * s;
        int ix = (int)ux, iy = (int)uy, iz = (int)uz;
        float dx = ux - (float)ix, dy = uy - (float)iy, dz = uz - (float)iz;
        unsigned a0 = (unsigned)ix;
        unsigned a1 = (unsigned)iy * PR1;
        unsigned a2 = (unsigned)iz * PR2;
        unsigned b0 = a0 + 1u, b1 = a1 + PR1, b2 = a2 + PR2;
        const float* Wl = W + (size_t)l * TBLN * 2u;
        float ax = 0.f, ay = 0.f;
        #pragma unroll
        for (int v = 0; v < 8; ++v) {
            unsigned h = ((v & 1) ? b0 : a0) ^ ((v & 2) ? b1 : a1) ^ ((v & 4) ? b2 : a2);
            h &= TMASK;
            float wx = (v & 1) ? dx : 1.f - dx;
            float wy = (v & 2) ? dy : 1.f - dy;
            float wz = (v & 4) ? dz : 1.f - dz;
            float w = (wx * wy) * wz;
            const float2 fvv = *reinterpret_cast<const float2*>(Wl + (size_t)h * 2u);
            ax = fmaf(fvv.x, w, ax);
            ay = fmaf(fvv.y, w, ay);
        }
        acc[2 * l + 0] = ax;
        acc[2 * l + 1] = ay;
    }
    float4* o = reinterpret_cast<float4*>(out + (size_t)n * (2 * NLEV));
    #pragma unroll
    for (int j = 0; j < 8; ++j)
        o[j] = make_float4(acc[4 * j + 0], acc[4 * j + 1], acc[4 * j + 2], acc[4 * j + 3]);
}

extern "C" void kernel_launch(void* const* d_in, const int* in_sizes, int n_in,
                              void* d_out, int out_size, void* d_ws, size_t ws_size,
                              hipStream_t stream) {
    const float* x = (const float*)d_in[0];
    const float* W = (const float*)d_in[1];
    float* out = (float*)d_out;
    int N = in_sizes[0] / 3;

    // numpy-exact scales: b = exp((log(2048)-log(16))/16); s_l = float32(16*b**l)
    ScaleArgs sc;
    double b = exp((log(2048.0) - log(16.0)) / 16.0);
    for (int l = 0; l < NLEV; ++l) {
        double p;
        switch (l) {
            case 0: p = 1.0; break;
            case 1: p = b;   break;
            case 2: p = b * b; break;
            default: p = pow(b, (double)l); break;
        }
        sc.s[l] = (float)(16.0 * p);
    }

    size_t whalf_u32 = (size_t)NLEV * TBLN;                 // 8.39M u32 = 33.5MB
    size_t scratch_u32 = (size_t)NLEV * (size_t)N;          // 32M u32 = 128MB
    size_t need = (whalf_u32 + scratch_u32) * sizeof(u32);

    if (ws_size >= need) {
        u32* Wh = (u32*)d_ws;
        u32* scratch = Wh + whalf_u32;

        int np4 = (int)(whalf_u32 / 4);                     // entries / 4 per thread
        hipLaunchKernelGGL(convert_w, dim3((np4 + 255) / 256), dim3(256), 0, stream,
                           W, Wh, np4);

        int TOT = (N + NPT - 1) / NPT;
        int gl = (TOT + 255) / 256;
        for (int l = 0; l < NLEV; ++l) {
            hipLaunchKernelGGL(level_kernel, dim3(gl), dim3(256), 0, stream,
                               x, Wh + (size_t)l * TBLN,
                               scratch + (size_t)l * (size_t)N,
                               sc.s[l], N, TOT);
        }
        int gt = (N + 255) / 256;
        hipLaunchKernelGGL(transpose_kernel, dim3(gt), dim3(256), 0, stream,
                           scratch, out, N);
    } else {
        int grid = (N + 255) / 256;
        hipLaunchKernelGGL(hashenc_fallback, dim3(grid), dim3(256), 0, stream,
                           x, W, out, sc, N);
    }
}